// Round 3
// baseline (455.456 us; speedup 1.0000x reference)
//
#include <hip/hip_runtime.h>

#define Bv 2
#define Tv 2048
#define Cv 2048
#define Hv 16
#define HKVv 4
#define HDv 128

typedef __attribute__((ext_vector_type(8))) __bf16 bf16x8;
typedef __attribute__((ext_vector_type(4))) float floatx4;
typedef __attribute__((ext_vector_type(16))) float floatx16;

__device__ __forceinline__ unsigned short f2b(float f) {
  unsigned int x = __float_as_uint(f);
  x += 0x7fffu + ((x >> 16) & 1u);
  return (unsigned short)(x >> 16);
}

#define MFMA(a, b, c) __builtin_amdgcn_mfma_f32_16x16x32_bf16((a), (b), (c), 0, 0, 0)
#define MFMA32(a, b, c) __builtin_amdgcn_mfma_f32_32x32x16_bf16((a), (b), (c), 0, 0, 0)

// async global->LDS, 16B per lane; dest = wave-uniform base + lane*16
__device__ __forceinline__ void gld_lds16(const void* g, void* l) {
  __builtin_amdgcn_global_load_lds((const __attribute__((address_space(1))) void*)g,
                                   (__attribute__((address_space(3))) void*)l, 16, 0, 0);
}

// ---------------- fp32 -> bf16 contiguous cast ----------------
__global__ void cvt_kernel(const float* __restrict__ src, unsigned short* __restrict__ dst, int n4) {
  int i = blockIdx.x * blockDim.x + threadIdx.x;
  if (i < n4) {
    float4 f = ((const float4*)src)[i];
    ushort4 u;
    u.x = f2b(f.x); u.y = f2b(f.y); u.z = f2b(f.z); u.w = f2b(f.w);
    ((ushort4*)dst)[i] = u;
  }
}

// ---------------- transpose + cast: src (K x N) fp32 -> dst (N x K) bf16 ----------------
__global__ void tcvt_kernel(const float* __restrict__ src, unsigned short* __restrict__ dst, int K, int N) {
  __shared__ float tile[32][33];
  int k0 = blockIdx.x * 32, n0 = blockIdx.y * 32;
  int tx = threadIdx.x, ty = threadIdx.y;
  for (int i = ty; i < 32; i += 8)
    tile[i][tx] = src[(size_t)(k0 + i) * N + n0 + tx];
  __syncthreads();
  for (int i = ty; i < 32; i += 8)
    dst[(size_t)(n0 + i) * K + k0 + tx] = f2b(tile[tx][i]);
}

// ---------------- fused QKV GEMM (m97-style staging + swizzled LDS) ----------------
__global__ __launch_bounds__(256) void gemm_qkv(
    const unsigned short* __restrict__ xb,
    const unsigned short* __restrict__ wq_t,   // 2048 x 2048 (N-major)
    const unsigned short* __restrict__ wkv_t,  // 1024 x 2048 (N-major)
    const float* __restrict__ bq, const float* __restrict__ bkv,
    unsigned short* __restrict__ qs,   // (B,H,T,HD)
    unsigned short* __restrict__ ks,   // (B,HKV,T,HD)
    unsigned short* __restrict__ vs) { // (B,HKV,HD,T)
  __shared__ __align__(16) unsigned short Ash[128 * 32];
  __shared__ __align__(16) unsigned short Bsh[128 * 32];
  int tid = threadIdx.x;
  int wave = tid >> 6, lane = tid & 63;
  int c = lane & 15, quad = lane >> 4;
  int wr = (wave >> 1) * 64, wc = (wave & 1) * 64;
  int m0 = blockIdx.x * 128, n0 = blockIdx.y * 128;
  bool isq = (n0 < 2048);
  const unsigned short* wt = isq ? (wq_t + (size_t)n0 * 2048)
                                 : (wkv_t + (size_t)(n0 - 2048) * 2048);
  floatx4 zero4 = {0.f, 0.f, 0.f, 0.f};
  floatx4 acc[4][4];
#pragma unroll
  for (int i = 0; i < 4; i++)
#pragma unroll
    for (int j = 0; j < 4; j++) acc[i][j] = zero4;

  const unsigned short* Abase = xb + (size_t)m0 * 2048;
  int s0 = wave * 128 + lane, s1 = wave * 128 + 64 + lane;
  int r0 = s0 >> 2, kc0 = (s0 & 3) ^ (r0 & 3);
  int r1 = s1 >> 2, kc1 = (s1 & 3) ^ (r1 & 3);
  int swz3 = quad ^ (c & 3);

  for (int k0 = 0; k0 < 2048; k0 += 32) {
    gld_lds16(Abase + (size_t)r0 * 2048 + k0 + kc0 * 8, Ash + (size_t)(wave * 128) * 8);
    gld_lds16(Abase + (size_t)r1 * 2048 + k0 + kc1 * 8, Ash + (size_t)(wave * 128 + 64) * 8);
    gld_lds16(wt + (size_t)r0 * 2048 + k0 + kc0 * 8, Bsh + (size_t)(wave * 128) * 8);
    gld_lds16(wt + (size_t)r1 * 2048 + k0 + kc1 * 8, Bsh + (size_t)(wave * 128 + 64) * 8);
    __syncthreads();
    bf16x8 af[4], bfv[4];
#pragma unroll
    for (int i = 0; i < 4; i++)
      af[i] = *(const bf16x8*)(&Ash[(wr + i * 16 + c) * 32 + swz3 * 8]);
#pragma unroll
    for (int j = 0; j < 4; j++)
      bfv[j] = *(const bf16x8*)(&Bsh[(wc + j * 16 + c) * 32 + swz3 * 8]);
#pragma unroll
    for (int i = 0; i < 4; i++)
#pragma unroll
      for (int j = 0; j < 4; j++)
        acc[i][j] = MFMA(af[i], bfv[j], acc[i][j]);
    __syncthreads();
  }

#pragma unroll
  for (int i = 0; i < 4; i++) {
#pragma unroll
    for (int j = 0; j < 4; j++) {
#pragma unroll
      for (int r = 0; r < 4; r++) {
        int m = m0 + wr + i * 16 + quad * 4 + r;
        int n = n0 + wc + j * 16 + c;
        int bidx = m >> 11, t = m & 2047;
        float val = acc[i][j][r];
        if (isq) {
          val = (val + bq[n]) * 0.08838834764831845f;  // 1/sqrt(128)
          int hh = n >> 7, d = n & 127;
          qs[((size_t)((bidx * Hv + hh) * Tv) + t) * HDv + d] = f2b(val);
        } else {
          int n2 = n - 2048;
          val += bkv[n2];
          if (n2 < 512) {
            int hh = n2 >> 7, d = n2 & 127;
            ks[((size_t)((bidx * HKVv + hh) * Tv) + t) * HDv + d] = f2b(val);
          } else {
            int n3 = n2 - 512;
            int hh = n3 >> 7, d = n3 & 127;
            vs[((size_t)((bidx * HKVv + hh) * HDv) + d) * Tv + t] = f2b(val);
          }
        }
      }
    }
  }
}

// ---------------- causal flash attention v3 ----------------
// 32x32x16 MFMA, S^T = K·Q^T formulation. Block = 128 q rows (4 waves x 32),
// BN=64 kv/tile, double-buffered K/V LDS with cross-barrier prefetch, P stays
// in registers (intra-lane repack + 2 shfl_xor(32) per kv-step).
__global__ __launch_bounds__(256, 2) void attn_kernel(
    const unsigned short* __restrict__ qs,   // (B,H,T,HD), pre-scaled
    const unsigned short* __restrict__ ks,   // (B,HKV,T,HD)
    const unsigned short* __restrict__ vs,   // (B,HKV,HD,T)
    unsigned short* __restrict__ ys) {       // (B,T,C) bf16
  __shared__ __align__(16) unsigned short Ksh[2][64 * 128];   // [kv][d], 16-granule XOR swizzle
  __shared__ __align__(16) unsigned short Vsh[2][128 * 64];   // [d][kv], 8-granule XOR swizzle

  int qt = (gridDim.x - 1) - blockIdx.x;   // heavy blocks first (LPT)
  int h = blockIdx.y, b = blockIdx.z;
  int hkv = h & (HKVv - 1);
  int tid = threadIdx.x;
  int wave = tid >> 6, lane = tid & 63;
  int q5 = lane & 31, hi = lane >> 5;
  int q0w = qt * 128 + wave * 32;
  int qrow = q0w + q5;

  const unsigned short* qptr = qs + ((size_t)((b * Hv + h) * Tv) + q0w) * HDv;
  const unsigned short* kbase = ks + (size_t)((b * HKVv + hkv) * Tv) * HDv;
  const unsigned short* vbase = vs + (size_t)((b * HKVv + hkv) * HDv) * Tv;

  // Q fragments (B-operand, 32x32x16): B[n=q5][k=kc*16+hi*8+j]
  bf16x8 qf[8];
#pragma unroll
  for (int kc = 0; kc < 8; kc++)
    qf[kc] = *(const bf16x8*)(qptr + (size_t)q5 * HDv + kc * 16 + hi * 8);

  floatx16 o[4];
#pragma unroll
  for (int dt = 0; dt < 4; dt++)
#pragma unroll
    for (int r = 0; r < 16; r++) o[dt][r] = 0.f;
  float M = -1e30f, L = 0.f;

  // staging offsets (16B granules, XOR-swizzled)
  int kOff[4], vOff[4];
#pragma unroll
  for (int i = 0; i < 4; i++) {
    int s = wave * 256 + i * 64 + lane;
    int rk = s >> 4, gk = (s & 15) ^ (rk & 15);
    kOff[i] = rk * 128 + gk * 8;
    int rv = s >> 3, gv = (s & 7) ^ (rv & 7);
    vOff[i] = rv * Tv + gv * 8;
  }
  int ldsBase = (wave * 256) * 8;  // shorts

  int ntiles = 2 * qt + 2;

  // prefetch tile 0 into buffer 0
#pragma unroll
  for (int i = 0; i < 4; i++) gld_lds16(kbase + kOff[i], &Ksh[0][0] + ldsBase + i * 512);
#pragma unroll
  for (int i = 0; i < 4; i++) gld_lds16(vbase + vOff[i], &Vsh[0][0] + ldsBase + i * 512);
  __syncthreads();

  for (int kt = 0; kt < ntiles; kt++) {
    int kv0 = kt * 64;
    int cur = kt & 1;
    // prefetch next tile into other buffer (flies during compute below)
    if (kt + 1 < ntiles) {
      int kv1 = (kt + 1) * 64;
#pragma unroll
      for (int i = 0; i < 4; i++)
        gld_lds16(kbase + (size_t)kv1 * 128 + kOff[i], &Ksh[cur ^ 1][0] + ldsBase + i * 512);
#pragma unroll
      for (int i = 0; i < 4; i++)
        gld_lds16(vbase + kv1 + vOff[i], &Vsh[cur ^ 1][0] + ldsBase + i * 512);
    }

    if (kv0 <= q0w + 31) {   // wave-active
      const unsigned short* Kb = &Ksh[cur][0];
      const unsigned short* Vb = &Vsh[cur][0];
      // ---- S^T tiles: 2 kv-subtiles of 32
      floatx16 st[2];
#pragma unroll
      for (int sub = 0; sub < 2; sub++) {
#pragma unroll
        for (int r = 0; r < 16; r++) st[sub][r] = 0.f;
#pragma unroll
        for (int kc = 0; kc < 8; kc++) {
          bf16x8 kf = *(const bf16x8*)(&Kb[(sub * 32 + q5) * 128 + (((kc * 2 + hi) ^ (q5 & 15)) * 8)]);
          st[sub] = MFMA32(kf, qf[kc], st[sub]);
        }
      }
      // ---- causal mask (diagonal tiles only)
      if (kv0 + 63 > q0w) {
        int kvb = kv0 + 4 * hi - qrow;
#pragma unroll
        for (int sub = 0; sub < 2; sub++) {
#pragma unroll
          for (int r = 0; r < 16; r++) {
            int roff = (r & 3) + 8 * (r >> 2) + sub * 32;
            if (kvb + roff > 0) st[sub][r] = -1e30f;
          }
        }
      }
      // ---- online softmax: per-lane q col; reduce over 32 regs + xor(32)
      float mx = -1e30f;
#pragma unroll
      for (int sub = 0; sub < 2; sub++)
#pragma unroll
        for (int r = 0; r < 16; r++) mx = fmaxf(mx, st[sub][r]);
      mx = fmaxf(mx, __shfl_xor(mx, 32));
      float Mn = fmaxf(M, mx);
      float al = __expf(M - Mn);
      M = Mn;
      float p[2][16];
      float l = 0.f;
#pragma unroll
      for (int sub = 0; sub < 2; sub++)
#pragma unroll
        for (int r = 0; r < 16; r++) {
          p[sub][r] = __expf(st[sub][r] - Mn);
          l += p[sub][r];
        }
      l += __shfl_xor(l, 32);
      L = L * al + l;
#pragma unroll
      for (int dt = 0; dt < 4; dt++)
#pragma unroll
        for (int r = 0; r < 16; r++) o[dt][r] *= al;
      // ---- pack P: pk[m] = bf16x4 of kv {8m+0..3} (+4*hi), m = sub*4 + (reg>>2)
      unsigned int pk[8][2];
#pragma unroll
      for (int sub = 0; sub < 2; sub++)
#pragma unroll
        for (int m = 0; m < 4; m++) {
          pk[sub * 4 + m][0] = (unsigned int)f2b(p[sub][m * 4 + 0]) | ((unsigned int)f2b(p[sub][m * 4 + 1]) << 16);
          pk[sub * 4 + m][1] = (unsigned int)f2b(p[sub][m * 4 + 2]) | ((unsigned int)f2b(p[sub][m * 4 + 3]) << 16);
        }
      // ---- PV: O^T += V^T · P^T ; P B-frags assembled via shfl_xor(32)
#pragma unroll
      for (int ksp = 0; ksp < 4; ksp++) {
        int ml = 2 * ksp + hi;        // local pk index
        int mr = 2 * ksp + (hi ^ 1);  // what partner needs from us
        unsigned int r0 = __shfl_xor((int)pk[mr][0], 32);
        unsigned int r1 = __shfl_xor((int)pk[mr][1], 32);
        unsigned int w0 = hi ? r0 : pk[ml][0];
        unsigned int w1 = hi ? r1 : pk[ml][1];
        unsigned int w2 = hi ? pk[ml][0] : r0;
        unsigned int w3 = hi ? pk[ml][1] : r1;
        union { unsigned int u[4]; bf16x8 v; } pf;
        pf.u[0] = w0; pf.u[1] = w1; pf.u[2] = w2; pf.u[3] = w3;
#pragma unroll
        for (int dt = 0; dt < 4; dt++) {
          bf16x8 vf = *(const bf16x8*)(&Vb[(dt * 32 + q5) * 64 + (((ksp * 2 + hi) ^ (q5 & 7)) * 8)]);
          o[dt] = MFMA32(vf, pf.v, o[dt]);
        }
      }
    }
    __syncthreads();   // drains prefetch (vmcnt) + orders buffer reuse
  }

  // ---- epilogue: O^T (D layout) -> ys[b][qrow][h*128 + d], 8B packed stores
  float Li = 1.0f / L;
  size_t rowbase = ((size_t)(b * Tv + qrow)) * Cv + h * HDv;
#pragma unroll
  for (int dt = 0; dt < 4; dt++) {
#pragma unroll
    for (int m = 0; m < 4; m++) {
      int d = dt * 32 + 8 * m + 4 * hi;
      unsigned int lo = (unsigned int)f2b(o[dt][m * 4 + 0] * Li) | ((unsigned int)f2b(o[dt][m * 4 + 1] * Li) << 16);
      unsigned int hi2 = (unsigned int)f2b(o[dt][m * 4 + 2] * Li) | ((unsigned int)f2b(o[dt][m * 4 + 3] * Li) << 16);
      *(uint2*)(&ys[rowbase + d]) = make_uint2(lo, hi2);
    }
  }
}

// ---------------- output projection (m97-style staging + swizzled LDS) ----------------
__global__ __launch_bounds__(256) void gemm_proj(
    const unsigned short* __restrict__ ys,
    const unsigned short* __restrict__ wp_t,  // 2048 x 2048 (N-major)
    const float* __restrict__ bp,
    float* __restrict__ out) {
  __shared__ __align__(16) unsigned short Ash[128 * 32];
  __shared__ __align__(16) unsigned short Bsh[128 * 32];
  int tid = threadIdx.x;
  int wave = tid >> 6, lane = tid & 63;
  int c = lane & 15, quad = lane >> 4;
  int wr = (wave >> 1) * 64, wc = (wave & 1) * 64;
  int m0 = blockIdx.x * 128, n0 = blockIdx.y * 128;
  floatx4 zero4 = {0.f, 0.f, 0.f, 0.f};
  floatx4 acc[4][4];
#pragma unroll
  for (int i = 0; i < 4; i++)
#pragma unroll
    for (int j = 0; j < 4; j++) acc[i][j] = zero4;

  const unsigned short* Abase = ys + (size_t)m0 * 2048;
  const unsigned short* Bbase = wp_t + (size_t)n0 * 2048;
  int s0 = wave * 128 + lane, s1 = wave * 128 + 64 + lane;
  int r0 = s0 >> 2, kc0 = (s0 & 3) ^ (r0 & 3);
  int r1 = s1 >> 2, kc1 = (s1 & 3) ^ (r1 & 3);
  int swz3 = quad ^ (c & 3);

  for (int k0 = 0; k0 < 2048; k0 += 32) {
    gld_lds16(Abase + (size_t)r0 * 2048 + k0 + kc0 * 8, Ash + (size_t)(wave * 128) * 8);
    gld_lds16(Abase + (size_t)r1 * 2048 + k0 + kc1 * 8, Ash + (size_t)(wave * 128 + 64) * 8);
    gld_lds16(Bbase + (size_t)r0 * 2048 + k0 + kc0 * 8, Bsh + (size_t)(wave * 128) * 8);
    gld_lds16(Bbase + (size_t)r1 * 2048 + k0 + kc1 * 8, Bsh + (size_t)(wave * 128 + 64) * 8);
    __syncthreads();
    bf16x8 af[4], bfv[4];
#pragma unroll
    for (int i = 0; i < 4; i++)
      af[i] = *(const bf16x8*)(&Ash[(wr + i * 16 + c) * 32 + swz3 * 8]);
#pragma unroll
    for (int j = 0; j < 4; j++)
      bfv[j] = *(const bf16x8*)(&Bsh[(wc + j * 16 + c) * 32 + swz3 * 8]);
#pragma unroll
    for (int i = 0; i < 4; i++)
#pragma unroll
      for (int j = 0; j < 4; j++)
        acc[i][j] = MFMA(af[i], bfv[j], acc[i][j]);
    __syncthreads();
  }

#pragma unroll
  for (int i = 0; i < 4; i++) {
#pragma unroll
    for (int j = 0; j < 4; j++) {
#pragma unroll
      for (int r = 0; r < 4; r++) {
        int m = m0 + wr + i * 16 + quad * 4 + r;
        int n = n0 + wc + j * 16 + c;
        out[(size_t)m * 2048 + n] = acc[i][j][r] + bp[n];
      }
    }
  }
}

extern "C" void kernel_launch(void* const* d_in, const int* in_sizes, int n_in,
                              void* d_out, int out_size, void* d_ws, size_t ws_size,
                              hipStream_t stream) {
  (void)in_sizes; (void)n_in; (void)out_size; (void)ws_size;
  const float* x   = (const float*)d_in[0];
  const float* Wkv = (const float*)d_in[1];
  const float* bkv = (const float*)d_in[2];
  const float* Wq  = (const float*)d_in[3];
  const float* bq  = (const float*)d_in[4];
  const float* Wp  = (const float*)d_in[5];
  const float* bp  = (const float*)d_in[6];
  float* out = (float*)d_out;

  char* ws = (char*)d_ws;
  unsigned short* xb    = (unsigned short*)(ws + 0);          // 16.78 MB
  unsigned short* wq_t  = (unsigned short*)(ws + 16777216);   //  8.39 MB
  unsigned short* wkv_t = (unsigned short*)(ws + 25165824);   //  4.19 MB
  unsigned short* wp_t  = (unsigned short*)(ws + 29360128);   //  8.39 MB
  unsigned short* qs    = (unsigned short*)(ws + 37748736);   // 16.78 MB
  unsigned short* ks    = (unsigned short*)(ws + 54525952);   //  4.19 MB
  unsigned short* vs    = (unsigned short*)(ws + 58720256);   //  4.19 MB
  unsigned short* ysbuf = (unsigned short*)(ws + 62914560);   // 16.78 MB  (end 79.7 MB)

  cvt_kernel<<<8192, 256, 0, stream>>>(x, xb, 2097152);
  tcvt_kernel<<<dim3(64, 64), dim3(32, 8), 0, stream>>>(Wq, wq_t, 2048, 2048);
  tcvt_kernel<<<dim3(64, 32), dim3(32, 8), 0, stream>>>(Wkv, wkv_t, 2048, 1024);
  tcvt_kernel<<<dim3(64, 64), dim3(32, 8), 0, stream>>>(Wp, wp_t, 2048, 2048);
  gemm_qkv<<<dim3(32, 24), 256, 0, stream>>>(xb, wq_t, wkv_t, bq, bkv, qs, ks, vs);
  attn_kernel<<<dim3(16, 16, 2), 256, 0, stream>>>(qs, ks, vs, ysbuf);
  gemm_proj<<<dim3(32, 16), 256, 0, stream>>>(ysbuf, wp_t, bp, out);
}

// Round 4
// 369.711 us; speedup vs baseline: 1.2319x; 1.2319x over previous
//
#include <hip/hip_runtime.h>

#define Bv 2
#define Tv 2048
#define Cv 2048
#define Hv 16
#define HKVv 4
#define HDv 128

typedef __attribute__((ext_vector_type(8))) __bf16 bf16x8;
typedef __attribute__((ext_vector_type(4))) float floatx4;

__device__ __forceinline__ unsigned short f2b(float f) {
  unsigned int x = __float_as_uint(f);
  x += 0x7fffu + ((x >> 16) & 1u);
  return (unsigned short)(x >> 16);
}

#define MFMA(a, b, c) __builtin_amdgcn_mfma_f32_16x16x32_bf16((a), (b), (c), 0, 0, 0)

// async global->LDS, 16B per lane; dest = wave-uniform base + lane*16
__device__ __forceinline__ void gld_lds16(const void* g, void* l) {
  __builtin_amdgcn_global_load_lds((const __attribute__((address_space(1))) void*)g,
                                   (__attribute__((address_space(3))) void*)l, 16, 0, 0);
}

// ---------------- fp32 -> bf16 contiguous cast ----------------
__global__ void cvt_kernel(const float* __restrict__ src, unsigned short* __restrict__ dst, int n4) {
  int i = blockIdx.x * blockDim.x + threadIdx.x;
  if (i < n4) {
    float4 f = ((const float4*)src)[i];
    ushort4 u;
    u.x = f2b(f.x); u.y = f2b(f.y); u.z = f2b(f.z); u.w = f2b(f.w);
    ((ushort4*)dst)[i] = u;
  }
}

// ---------------- transpose + cast: src (K x N) fp32 -> dst (N x K) bf16 ----------------
__global__ void tcvt_kernel(const float* __restrict__ src, unsigned short* __restrict__ dst, int K, int N) {
  __shared__ float tile[32][33];
  int k0 = blockIdx.x * 32, n0 = blockIdx.y * 32;
  int tx = threadIdx.x, ty = threadIdx.y;
  for (int i = ty; i < 32; i += 8)
    tile[i][tx] = src[(size_t)(k0 + i) * N + n0 + tx];
  __syncthreads();
  for (int i = ty; i < 32; i += 8)
    dst[(size_t)(n0 + i) * K + k0 + tx] = f2b(tile[tx][i]);
}

// ---------------- fused QKV GEMM (m97-style staging + swizzled LDS) ----------------
__global__ __launch_bounds__(256) void gemm_qkv(
    const unsigned short* __restrict__ xb,
    const unsigned short* __restrict__ wq_t,   // 2048 x 2048 (N-major)
    const unsigned short* __restrict__ wkv_t,  // 1024 x 2048 (N-major)
    const float* __restrict__ bq, const float* __restrict__ bkv,
    unsigned short* __restrict__ qs,   // (B,H,T,HD)
    unsigned short* __restrict__ ks,   // (B,HKV,T,HD)
    unsigned short* __restrict__ vs) { // (B,HKV,HD,T)
  __shared__ __align__(16) unsigned short Ash[128 * 32];
  __shared__ __align__(16) unsigned short Bsh[128 * 32];
  int tid = threadIdx.x;
  int wave = tid >> 6, lane = tid & 63;
  int c = lane & 15, quad = lane >> 4;
  int wr = (wave >> 1) * 64, wc = (wave & 1) * 64;
  int m0 = blockIdx.x * 128, n0 = blockIdx.y * 128;
  bool isq = (n0 < 2048);
  const unsigned short* wt = isq ? (wq_t + (size_t)n0 * 2048)
                                 : (wkv_t + (size_t)(n0 - 2048) * 2048);
  floatx4 zero4 = {0.f, 0.f, 0.f, 0.f};
  floatx4 acc[4][4];
#pragma unroll
  for (int i = 0; i < 4; i++)
#pragma unroll
    for (int j = 0; j < 4; j++) acc[i][j] = zero4;

  const unsigned short* Abase = xb + (size_t)m0 * 2048;
  int s0 = wave * 128 + lane, s1 = wave * 128 + 64 + lane;
  int r0 = s0 >> 2, kc0 = (s0 & 3) ^ (r0 & 3);
  int r1 = s1 >> 2, kc1 = (s1 & 3) ^ (r1 & 3);
  int swz3 = quad ^ (c & 3);

  for (int k0 = 0; k0 < 2048; k0 += 32) {
    gld_lds16(Abase + (size_t)r0 * 2048 + k0 + kc0 * 8, Ash + (size_t)(wave * 128) * 8);
    gld_lds16(Abase + (size_t)r1 * 2048 + k0 + kc1 * 8, Ash + (size_t)(wave * 128 + 64) * 8);
    gld_lds16(wt + (size_t)r0 * 2048 + k0 + kc0 * 8, Bsh + (size_t)(wave * 128) * 8);
    gld_lds16(wt + (size_t)r1 * 2048 + k0 + kc1 * 8, Bsh + (size_t)(wave * 128 + 64) * 8);
    __syncthreads();
    bf16x8 af[4], bfv[4];
#pragma unroll
    for (int i = 0; i < 4; i++)
      af[i] = *(const bf16x8*)(&Ash[(wr + i * 16 + c) * 32 + swz3 * 8]);
#pragma unroll
    for (int j = 0; j < 4; j++)
      bfv[j] = *(const bf16x8*)(&Bsh[(wc + j * 16 + c) * 32 + swz3 * 8]);
#pragma unroll
    for (int i = 0; i < 4; i++)
#pragma unroll
      for (int j = 0; j < 4; j++)
        acc[i][j] = MFMA(af[i], bfv[j], acc[i][j]);
    __syncthreads();
  }

#pragma unroll
  for (int i = 0; i < 4; i++) {
#pragma unroll
    for (int j = 0; j < 4; j++) {
#pragma unroll
      for (int r = 0; r < 4; r++) {
        int m = m0 + wr + i * 16 + quad * 4 + r;
        int n = n0 + wc + j * 16 + c;
        int bidx = m >> 11, t = m & 2047;
        float val = acc[i][j][r];
        if (isq) {
          val = (val + bq[n]) * 0.08838834764831845f;  // 1/sqrt(128)
          int hh = n >> 7, d = n & 127;
          qs[((size_t)((bidx * Hv + hh) * Tv) + t) * HDv + d] = f2b(val);
        } else {
          int n2 = n - 2048;
          val += bkv[n2];
          if (n2 < 512) {
            int hh = n2 >> 7, d = n2 & 127;
            ks[((size_t)((bidx * HKVv + hh) * Tv) + t) * HDv + d] = f2b(val);
          } else {
            int n3 = n2 - 512;
            int hh = n3 >> 7, d = n3 & 127;
            vs[((size_t)((bidx * HKVv + hh) * HDv) + d) * Tv + t] = f2b(val);
          }
        }
      }
    }
  }
}

// ---------------- causal flash attention v4 ----------------
// R2 shape (wave=16 q rows, BN=32, MFMA16, S^T form) + R3 pipelining
// (double-buffered K/V, cross-barrier prefetch, 1 barrier/tile) at 36 KB LDS
// -> 4 blocks/CU. qt derived from (x,h) so each CU's resident set has
// uniform total work (qt pairs summing to 31).
__global__ __launch_bounds__(256, 4) void attn_kernel(
    const unsigned short* __restrict__ qs,   // (B,H,T,HD), pre-scaled
    const unsigned short* __restrict__ ks,   // (B,HKV,T,HD)
    const unsigned short* __restrict__ vs,   // (B,HKV,HD,T)
    unsigned short* __restrict__ ys) {       // (B,T,C) bf16
  __shared__ __align__(16) unsigned short Ksh[2][32 * 128];  // [kv][d]
  __shared__ __align__(16) unsigned short Vsh[2][128 * 32];  // [d][kv]
  __shared__ __align__(16) unsigned short Psh[4][16 * 32];   // per-wave [q][kv]

  int x = blockIdx.x, h = blockIdx.y, b = blockIdx.z;
  int qt = (h & 8) ? (31 - x) : x;   // balance: CU-resident blocks pair qt + (31-qt)
  int hkv = h & (HKVv - 1);
  int tid = threadIdx.x;
  int wave = tid >> 6, lane = tid & 63;
  int c = lane & 15, quad = lane >> 4;
  int q0w = qt * 64 + wave * 16;
  int qrow = q0w + c;
  int swzK = c & 7, swzV = c & 3;

  const unsigned short* qptr = qs + ((size_t)((b * Hv + h) * Tv) + q0w) * HDv;
  const unsigned short* kbase = ks + (size_t)((b * HKVv + hkv) * Tv) * HDv;
  const unsigned short* vbase = vs + (size_t)((b * HKVv + hkv) * HDv) * Tv;

  // Q fragment (B-operand): B[n=c][k=kc*32+quad*8+j]
  bf16x8 qf[4];
#pragma unroll
  for (int kc = 0; kc < 4; kc++)
    qf[kc] = *(const bf16x8*)(qptr + (size_t)c * HDv + kc * 32 + quad * 8);

  floatx4 zero4 = {0.f, 0.f, 0.f, 0.f};
  floatx4 o[8];
#pragma unroll
  for (int dt = 0; dt < 8; dt++) o[dt] = zero4;
  float M = -1e30f, L = 0.f;

  unsigned short* Pw = &Psh[wave][0];

  // staging offsets (16B granules, XOR-swizzled). K: 512 granules (32 rows x 16 g).
  // V: 512 granules (128 rows x 4 g). slot = wave*128 + i*64 + lane, i<2.
  int kOff[2], vOff[2];
#pragma unroll
  for (int i = 0; i < 2; i++) {
    int s = wave * 128 + i * 64 + lane;
    int rk = s >> 4, gk = (s & 15) ^ (rk & 7);
    kOff[i] = rk * 128 + gk * 8;
    int rv = s >> 2, gv = (s & 3) ^ (rv & 3);
    vOff[i] = rv * Tv + gv * 8;
  }
  int ldsBase = (wave * 128) * 8;  // shorts

  int ntiles = 2 * qt + 2;

  // prologue: prefetch tile 0 into buffer 0
#pragma unroll
  for (int i = 0; i < 2; i++) gld_lds16(kbase + kOff[i], &Ksh[0][0] + ldsBase + i * 512);
#pragma unroll
  for (int i = 0; i < 2; i++) gld_lds16(vbase + vOff[i], &Vsh[0][0] + ldsBase + i * 512);
  __syncthreads();

  for (int kt = 0; kt < ntiles; kt++) {
    int kv0 = kt * 32;
    int cur = kt & 1;
    // prefetch next tile into other buffer (in flight during compute)
    if (kt + 1 < ntiles) {
      int kv1 = (kt + 1) * 32;
#pragma unroll
      for (int i = 0; i < 2; i++)
        gld_lds16(kbase + (size_t)kv1 * 128 + kOff[i], &Ksh[cur ^ 1][0] + ldsBase + i * 512);
#pragma unroll
      for (int i = 0; i < 2; i++)
        gld_lds16(vbase + kv1 + vOff[i], &Vsh[cur ^ 1][0] + ldsBase + i * 512);
    }

    if (kv0 <= q0w + 15) {   // wave-active
      const unsigned short* Kb = &Ksh[cur][0];
      const unsigned short* Vb = &Vsh[cur][0];
      // ---- S^T = K·Q^T : 2 kv-subtiles of 16
      floatx4 st[2] = {zero4, zero4};
#pragma unroll
      for (int kc = 0; kc < 4; kc++) {
#pragma unroll
        for (int sub = 0; sub < 2; sub++) {
          bf16x8 kf = *(const bf16x8*)(&Kb[(sub * 16 + c) * 128 + (((kc * 4 + quad) ^ swzK) * 8)]);
          st[sub] = MFMA(kf, qf[kc], st[sub]);
        }
      }
      // ---- causal mask (diagonal tiles only)
      if (kv0 + 31 > q0w) {
#pragma unroll
        for (int sub = 0; sub < 2; sub++) {
          int kvb = kv0 + sub * 16 + quad * 4;
#pragma unroll
          for (int r = 0; r < 4; r++)
            if (kvb + r > qrow) st[sub][r] = -1e30f;
        }
      }
      // ---- online softmax (per-lane qrow = c; reduce regs + quad axis)
      float mx = -1e30f;
#pragma unroll
      for (int sub = 0; sub < 2; sub++)
        mx = fmaxf(mx, fmaxf(fmaxf(st[sub][0], st[sub][1]), fmaxf(st[sub][2], st[sub][3])));
      mx = fmaxf(mx, __shfl_xor(mx, 16));
      mx = fmaxf(mx, __shfl_xor(mx, 32));
      float Mn = fmaxf(M, mx);
      float al = __expf(M - Mn);
      M = Mn;
      float l = 0.f;
#pragma unroll
      for (int sub = 0; sub < 2; sub++) {
        float p0 = __expf(st[sub][0] - Mn);
        float p1 = __expf(st[sub][1] - Mn);
        float p2 = __expf(st[sub][2] - Mn);
        float p3 = __expf(st[sub][3] - Mn);
        l += (p0 + p1) + (p2 + p3);
        unsigned int lo = (unsigned int)f2b(p0) | ((unsigned int)f2b(p1) << 16);
        unsigned int hi = (unsigned int)f2b(p2) | ((unsigned int)f2b(p3) << 16);
        int g = (sub * 2 + (quad >> 1)) ^ swzV;
        *(uint2*)(&Pw[c * 32 + g * 8 + (quad & 1) * 4]) = make_uint2(lo, hi);
      }
      l += __shfl_xor(l, 16);
      l += __shfl_xor(l, 32);
      L = L * al + l;
#pragma unroll
      for (int dt = 0; dt < 8; dt++) o[dt] *= al;
      // ---- PV: O^T += V^T·P^T (wave-local P; lgkmcnt orders write->read)
      bf16x8 pf = *(const bf16x8*)(&Pw[c * 32 + ((quad ^ swzV) * 8)]);
#pragma unroll
      for (int dt = 0; dt < 8; dt++) {
        bf16x8 vf = *(const bf16x8*)(&Vb[(dt * 16 + c) * 32 + ((quad ^ swzV) * 8)]);
        o[dt] = MFMA(vf, pf, o[dt]);
      }
    }
    __syncthreads();   // drains prefetch (vmcnt) + orders buffer reuse
  }

  // ---- epilogue: O^T C-layout -> ys[b][qrow][h*128 + d], packed 8B stores
  float Li = 1.0f / L;
  size_t rowbase = ((size_t)(b * Tv + qrow)) * Cv + h * HDv;
#pragma unroll
  for (int dt = 0; dt < 8; dt++) {
    unsigned int lo = (unsigned int)f2b(o[dt][0] * Li) | ((unsigned int)f2b(o[dt][1] * Li) << 16);
    unsigned int hi2 = (unsigned int)f2b(o[dt][2] * Li) | ((unsigned int)f2b(o[dt][3] * Li) << 16);
    *(uint2*)(&ys[rowbase + dt * 16 + quad * 4]) = make_uint2(lo, hi2);
  }
}

// ---------------- output projection (m97-style staging + swizzled LDS) ----------------
__global__ __launch_bounds__(256) void gemm_proj(
    const unsigned short* __restrict__ ys,
    const unsigned short* __restrict__ wp_t,  // 2048 x 2048 (N-major)
    const float* __restrict__ bp,
    float* __restrict__ out) {
  __shared__ __align__(16) unsigned short Ash[128 * 32];
  __shared__ __align__(16) unsigned short Bsh[128 * 32];
  int tid = threadIdx.x;
  int wave = tid >> 6, lane = tid & 63;
  int c = lane & 15, quad = lane >> 4;
  int wr = (wave >> 1) * 64, wc = (wave & 1) * 64;
  int m0 = blockIdx.x * 128, n0 = blockIdx.y * 128;
  floatx4 zero4 = {0.f, 0.f, 0.f, 0.f};
  floatx4 acc[4][4];
#pragma unroll
  for (int i = 0; i < 4; i++)
#pragma unroll
    for (int j = 0; j < 4; j++) acc[i][j] = zero4;

  const unsigned short* Abase = ys + (size_t)m0 * 2048;
  const unsigned short* Bbase = wp_t + (size_t)n0 * 2048;
  int s0 = wave * 128 + lane, s1 = wave * 128 + 64 + lane;
  int r0 = s0 >> 2, kc0 = (s0 & 3) ^ (r0 & 3);
  int r1 = s1 >> 2, kc1 = (s1 & 3) ^ (r1 & 3);
  int swz3 = quad ^ (c & 3);

  for (int k0 = 0; k0 < 2048; k0 += 32) {
    gld_lds16(Abase + (size_t)r0 * 2048 + k0 + kc0 * 8, Ash + (size_t)(wave * 128) * 8);
    gld_lds16(Abase + (size_t)r1 * 2048 + k0 + kc1 * 8, Ash + (size_t)(wave * 128 + 64) * 8);
    gld_lds16(Bbase + (size_t)r0 * 2048 + k0 + kc0 * 8, Bsh + (size_t)(wave * 128) * 8);
    gld_lds16(Bbase + (size_t)r1 * 2048 + k0 + kc1 * 8, Bsh + (size_t)(wave * 128 + 64) * 8);
    __syncthreads();
    bf16x8 af[4], bfv[4];
#pragma unroll
    for (int i = 0; i < 4; i++)
      af[i] = *(const bf16x8*)(&Ash[(wr + i * 16 + c) * 32 + swz3 * 8]);
#pragma unroll
    for (int j = 0; j < 4; j++)
      bfv[j] = *(const bf16x8*)(&Bsh[(wc + j * 16 + c) * 32 + swz3 * 8]);
#pragma unroll
    for (int i = 0; i < 4; i++)
#pragma unroll
      for (int j = 0; j < 4; j++)
        acc[i][j] = MFMA(af[i], bfv[j], acc[i][j]);
    __syncthreads();
  }

#pragma unroll
  for (int i = 0; i < 4; i++) {
#pragma unroll
    for (int j = 0; j < 4; j++) {
#pragma unroll
      for (int r = 0; r < 4; r++) {
        int m = m0 + wr + i * 16 + quad * 4 + r;
        int n = n0 + wc + j * 16 + c;
        out[(size_t)m * 2048 + n] = acc[i][j][r] + bp[n];
      }
    }
  }
}

extern "C" void kernel_launch(void* const* d_in, const int* in_sizes, int n_in,
                              void* d_out, int out_size, void* d_ws, size_t ws_size,
                              hipStream_t stream) {
  (void)in_sizes; (void)n_in; (void)out_size; (void)ws_size;
  const float* x   = (const float*)d_in[0];
  const float* Wkv = (const float*)d_in[1];
  const float* bkv = (const float*)d_in[2];
  const float* Wq  = (const float*)d_in[3];
  const float* bq  = (const float*)d_in[4];
  const float* Wp  = (const float*)d_in[5];
  const float* bp  = (const float*)d_in[6];
  float* out = (float*)d_out;

  char* ws = (char*)d_ws;
  unsigned short* xb    = (unsigned short*)(ws + 0);          // 16.78 MB
  unsigned short* wq_t  = (unsigned short*)(ws + 16777216);   //  8.39 MB
  unsigned short* wkv_t = (unsigned short*)(ws + 25165824);   //  4.19 MB
  unsigned short* wp_t  = (unsigned short*)(ws + 29360128);   //  8.39 MB
  unsigned short* qs    = (unsigned short*)(ws + 37748736);   // 16.78 MB
  unsigned short* ks    = (unsigned short*)(ws + 54525952);   //  4.19 MB
  unsigned short* vs    = (unsigned short*)(ws + 58720256);   //  4.19 MB
  unsigned short* ysbuf = (unsigned short*)(ws + 62914560);   // 16.78 MB  (end 79.7 MB)

  cvt_kernel<<<8192, 256, 0, stream>>>(x, xb, 2097152);
  tcvt_kernel<<<dim3(64, 64), dim3(32, 8), 0, stream>>>(Wq, wq_t, 2048, 2048);
  tcvt_kernel<<<dim3(64, 32), dim3(32, 8), 0, stream>>>(Wkv, wkv_t, 2048, 1024);
  tcvt_kernel<<<dim3(64, 64), dim3(32, 8), 0, stream>>>(Wp, wp_t, 2048, 2048);
  gemm_qkv<<<dim3(32, 24), 256, 0, stream>>>(xb, wq_t, wkv_t, bq, bkv, qs, ks, vs);
  attn_kernel<<<dim3(32, 16, 2), 256, 0, stream>>>(qs, ks, vs, ysbuf);
  gemm_proj<<<dim3(32, 16), 256, 0, stream>>>(ysbuf, wp_t, bp, out);
}

// Round 5
// 349.566 us; speedup vs baseline: 1.3029x; 1.0576x over previous
//
#include <hip/hip_runtime.h>

#define Bv 2
#define Tv 2048
#define Cv 2048
#define Hv 16
#define HKVv 4
#define HDv 128

typedef __attribute__((ext_vector_type(8))) __bf16 bf16x8;
typedef __attribute__((ext_vector_type(4))) float floatx4;

__device__ __forceinline__ unsigned short f2b(float f) {
  unsigned int x = __float_as_uint(f);
  x += 0x7fffu + ((x >> 16) & 1u);
  return (unsigned short)(x >> 16);
}

#define MFMA(a, b, c) __builtin_amdgcn_mfma_f32_16x16x32_bf16((a), (b), (c), 0, 0, 0)

// async global->LDS, 16B per lane; dest = wave-uniform base + lane*16
__device__ __forceinline__ void gld_lds16(const void* g, void* l) {
  __builtin_amdgcn_global_load_lds((const __attribute__((address_space(1))) void*)g,
                                   (__attribute__((address_space(3))) void*)l, 16, 0, 0);
}

// ---------------- fp32 -> bf16 contiguous cast ----------------
__global__ void cvt_kernel(const float* __restrict__ src, unsigned short* __restrict__ dst, int n4) {
  int i = blockIdx.x * blockDim.x + threadIdx.x;
  if (i < n4) {
    float4 f = ((const float4*)src)[i];
    ushort4 u;
    u.x = f2b(f.x); u.y = f2b(f.y); u.z = f2b(f.z); u.w = f2b(f.w);
    ((ushort4*)dst)[i] = u;
  }
}

// ---------------- transpose + cast: src (K x N) fp32 -> dst (N x K) bf16 ----------------
__global__ void tcvt_kernel(const float* __restrict__ src, unsigned short* __restrict__ dst, int K, int N) {
  __shared__ float tile[32][33];
  int k0 = blockIdx.x * 32, n0 = blockIdx.y * 32;
  int tx = threadIdx.x, ty = threadIdx.y;
  for (int i = ty; i < 32; i += 8)
    tile[i][tx] = src[(size_t)(k0 + i) * N + n0 + tx];
  __syncthreads();
  for (int i = ty; i < 32; i += 8)
    dst[(size_t)(n0 + i) * K + k0 + tx] = f2b(tile[tx][i]);
}

// ---------------- fused QKV GEMM: dbuf LDS + cross-barrier prefetch ----------------
__global__ __launch_bounds__(256) void gemm_qkv(
    const unsigned short* __restrict__ xb,
    const unsigned short* __restrict__ wq_t,   // 2048 x 2048 (N-major)
    const unsigned short* __restrict__ wkv_t,  // 1024 x 2048 (N-major)
    const float* __restrict__ bq, const float* __restrict__ bkv,
    unsigned short* __restrict__ qs,   // (B,H,T,HD)
    unsigned short* __restrict__ ks,   // (B,HKV,T,HD)
    unsigned short* __restrict__ vs) { // (B,HKV,HD,T)
  __shared__ __align__(16) unsigned short Ash[2][128 * 32];
  __shared__ __align__(16) unsigned short Bsh[2][128 * 32];
  int tid = threadIdx.x;
  int wave = tid >> 6, lane = tid & 63;
  int c = lane & 15, quad = lane >> 4;
  int wr = (wave >> 1) * 64, wc = (wave & 1) * 64;
  int m0 = blockIdx.x * 128, n0 = blockIdx.y * 128;
  bool isq = (n0 < 2048);
  const unsigned short* wt = isq ? (wq_t + (size_t)n0 * 2048)
                                 : (wkv_t + (size_t)(n0 - 2048) * 2048);
  floatx4 zero4 = {0.f, 0.f, 0.f, 0.f};
  floatx4 acc[4][4];
#pragma unroll
  for (int i = 0; i < 4; i++)
#pragma unroll
    for (int j = 0; j < 4; j++) acc[i][j] = zero4;

  const unsigned short* Abase = xb + (size_t)m0 * 2048;
  int s0 = wave * 128 + lane, s1 = wave * 128 + 64 + lane;
  int r0 = s0 >> 2, kc0 = (s0 & 3) ^ (r0 & 3);
  int r1 = s1 >> 2, kc1 = (s1 & 3) ^ (r1 & 3);
  int swz3 = quad ^ (c & 3);
  int dA0 = (wave * 128) * 8, dA1 = (wave * 128 + 64) * 8;

  // prologue: prefetch K-step 0 into buffer 0
  gld_lds16(Abase + (size_t)r0 * 2048 + kc0 * 8, &Ash[0][0] + dA0);
  gld_lds16(Abase + (size_t)r1 * 2048 + kc1 * 8, &Ash[0][0] + dA1);
  gld_lds16(wt + (size_t)r0 * 2048 + kc0 * 8, &Bsh[0][0] + dA0);
  gld_lds16(wt + (size_t)r1 * 2048 + kc1 * 8, &Bsh[0][0] + dA1);
  __syncthreads();

  for (int it = 0; it < 64; it++) {
    int cur = it & 1;
    if (it + 1 < 64) {   // prefetch next K-step; in flight during MFMA below
      int k1 = (it + 1) * 32;
      gld_lds16(Abase + (size_t)r0 * 2048 + k1 + kc0 * 8, &Ash[cur ^ 1][0] + dA0);
      gld_lds16(Abase + (size_t)r1 * 2048 + k1 + kc1 * 8, &Ash[cur ^ 1][0] + dA1);
      gld_lds16(wt + (size_t)r0 * 2048 + k1 + kc0 * 8, &Bsh[cur ^ 1][0] + dA0);
      gld_lds16(wt + (size_t)r1 * 2048 + k1 + kc1 * 8, &Bsh[cur ^ 1][0] + dA1);
    }
    bf16x8 af[4], bfv[4];
#pragma unroll
    for (int i = 0; i < 4; i++)
      af[i] = *(const bf16x8*)(&Ash[cur][(wr + i * 16 + c) * 32 + swz3 * 8]);
#pragma unroll
    for (int j = 0; j < 4; j++)
      bfv[j] = *(const bf16x8*)(&Bsh[cur][(wc + j * 16 + c) * 32 + swz3 * 8]);
#pragma unroll
    for (int i = 0; i < 4; i++)
#pragma unroll
      for (int j = 0; j < 4; j++)
        acc[i][j] = MFMA(af[i], bfv[j], acc[i][j]);
    __syncthreads();   // drains prefetch (vmcnt) + protects buffer reuse
  }

#pragma unroll
  for (int i = 0; i < 4; i++) {
#pragma unroll
    for (int j = 0; j < 4; j++) {
#pragma unroll
      for (int r = 0; r < 4; r++) {
        int m = m0 + wr + i * 16 + quad * 4 + r;
        int n = n0 + wc + j * 16 + c;
        int bidx = m >> 11, t = m & 2047;
        float val = acc[i][j][r];
        if (isq) {
          val = (val + bq[n]) * 0.08838834764831845f;  // 1/sqrt(128)
          int hh = n >> 7, d = n & 127;
          qs[((size_t)((bidx * Hv + hh) * Tv) + t) * HDv + d] = f2b(val);
        } else {
          int n2 = n - 2048;
          val += bkv[n2];
          if (n2 < 512) {
            int hh = n2 >> 7, d = n2 & 127;
            ks[((size_t)((bidx * HKVv + hh) * Tv) + t) * HDv + d] = f2b(val);
          } else {
            int n3 = n2 - 512;
            int hh = n3 >> 7, d = n3 & 127;
            vs[((size_t)((bidx * HKVv + hh) * HDv) + d) * Tv + t] = f2b(val);
          }
        }
      }
    }
  }
}

// ---------------- causal flash attention v4 (unchanged from R4) ----------------
__global__ __launch_bounds__(256, 4) void attn_kernel(
    const unsigned short* __restrict__ qs,   // (B,H,T,HD), pre-scaled
    const unsigned short* __restrict__ ks,   // (B,HKV,T,HD)
    const unsigned short* __restrict__ vs,   // (B,HKV,HD,T)
    unsigned short* __restrict__ ys) {       // (B,T,C) bf16
  __shared__ __align__(16) unsigned short Ksh[2][32 * 128];  // [kv][d]
  __shared__ __align__(16) unsigned short Vsh[2][128 * 32];  // [d][kv]
  __shared__ __align__(16) unsigned short Psh[4][16 * 32];   // per-wave [q][kv]

  int x = blockIdx.x, h = blockIdx.y, b = blockIdx.z;
  int qt = (h & 8) ? (31 - x) : x;   // balance: CU-resident blocks pair qt + (31-qt)
  int hkv = h & (HKVv - 1);
  int tid = threadIdx.x;
  int wave = tid >> 6, lane = tid & 63;
  int c = lane & 15, quad = lane >> 4;
  int q0w = qt * 64 + wave * 16;
  int qrow = q0w + c;
  int swzK = c & 7, swzV = c & 3;

  const unsigned short* qptr = qs + ((size_t)((b * Hv + h) * Tv) + q0w) * HDv;
  const unsigned short* kbase = ks + (size_t)((b * HKVv + hkv) * Tv) * HDv;
  const unsigned short* vbase = vs + (size_t)((b * HKVv + hkv) * HDv) * Tv;

  bf16x8 qf[4];
#pragma unroll
  for (int kc = 0; kc < 4; kc++)
    qf[kc] = *(const bf16x8*)(qptr + (size_t)c * HDv + kc * 32 + quad * 8);

  floatx4 zero4 = {0.f, 0.f, 0.f, 0.f};
  floatx4 o[8];
#pragma unroll
  for (int dt = 0; dt < 8; dt++) o[dt] = zero4;
  float M = -1e30f, L = 0.f;

  unsigned short* Pw = &Psh[wave][0];

  int kOff[2], vOff[2];
#pragma unroll
  for (int i = 0; i < 2; i++) {
    int s = wave * 128 + i * 64 + lane;
    int rk = s >> 4, gk = (s & 15) ^ (rk & 7);
    kOff[i] = rk * 128 + gk * 8;
    int rv = s >> 2, gv = (s & 3) ^ (rv & 3);
    vOff[i] = rv * Tv + gv * 8;
  }
  int ldsBase = (wave * 128) * 8;  // shorts

  int ntiles = 2 * qt + 2;

#pragma unroll
  for (int i = 0; i < 2; i++) gld_lds16(kbase + kOff[i], &Ksh[0][0] + ldsBase + i * 512);
#pragma unroll
  for (int i = 0; i < 2; i++) gld_lds16(vbase + vOff[i], &Vsh[0][0] + ldsBase + i * 512);
  __syncthreads();

  for (int kt = 0; kt < ntiles; kt++) {
    int kv0 = kt * 32;
    int cur = kt & 1;
    if (kt + 1 < ntiles) {
      int kv1 = (kt + 1) * 32;
#pragma unroll
      for (int i = 0; i < 2; i++)
        gld_lds16(kbase + (size_t)kv1 * 128 + kOff[i], &Ksh[cur ^ 1][0] + ldsBase + i * 512);
#pragma unroll
      for (int i = 0; i < 2; i++)
        gld_lds16(vbase + kv1 + vOff[i], &Vsh[cur ^ 1][0] + ldsBase + i * 512);
    }

    if (kv0 <= q0w + 15) {   // wave-active
      const unsigned short* Kb = &Ksh[cur][0];
      const unsigned short* Vb = &Vsh[cur][0];
      floatx4 st[2] = {zero4, zero4};
#pragma unroll
      for (int kc = 0; kc < 4; kc++) {
#pragma unroll
        for (int sub = 0; sub < 2; sub++) {
          bf16x8 kf = *(const bf16x8*)(&Kb[(sub * 16 + c) * 128 + (((kc * 4 + quad) ^ swzK) * 8)]);
          st[sub] = MFMA(kf, qf[kc], st[sub]);
        }
      }
      if (kv0 + 31 > q0w) {
#pragma unroll
        for (int sub = 0; sub < 2; sub++) {
          int kvb = kv0 + sub * 16 + quad * 4;
#pragma unroll
          for (int r = 0; r < 4; r++)
            if (kvb + r > qrow) st[sub][r] = -1e30f;
        }
      }
      float mx = -1e30f;
#pragma unroll
      for (int sub = 0; sub < 2; sub++)
        mx = fmaxf(mx, fmaxf(fmaxf(st[sub][0], st[sub][1]), fmaxf(st[sub][2], st[sub][3])));
      mx = fmaxf(mx, __shfl_xor(mx, 16));
      mx = fmaxf(mx, __shfl_xor(mx, 32));
      float Mn = fmaxf(M, mx);
      float al = __expf(M - Mn);
      M = Mn;
      float l = 0.f;
#pragma unroll
      for (int sub = 0; sub < 2; sub++) {
        float p0 = __expf(st[sub][0] - Mn);
        float p1 = __expf(st[sub][1] - Mn);
        float p2 = __expf(st[sub][2] - Mn);
        float p3 = __expf(st[sub][3] - Mn);
        l += (p0 + p1) + (p2 + p3);
        unsigned int lo = (unsigned int)f2b(p0) | ((unsigned int)f2b(p1) << 16);
        unsigned int hi = (unsigned int)f2b(p2) | ((unsigned int)f2b(p3) << 16);
        int g = (sub * 2 + (quad >> 1)) ^ swzV;
        *(uint2*)(&Pw[c * 32 + g * 8 + (quad & 1) * 4]) = make_uint2(lo, hi);
      }
      l += __shfl_xor(l, 16);
      l += __shfl_xor(l, 32);
      L = L * al + l;
#pragma unroll
      for (int dt = 0; dt < 8; dt++) o[dt] *= al;
      bf16x8 pf = *(const bf16x8*)(&Pw[c * 32 + ((quad ^ swzV) * 8)]);
#pragma unroll
      for (int dt = 0; dt < 8; dt++) {
        bf16x8 vf = *(const bf16x8*)(&Vb[(dt * 16 + c) * 32 + ((quad ^ swzV) * 8)]);
        o[dt] = MFMA(vf, pf, o[dt]);
      }
    }
    __syncthreads();   // drains prefetch (vmcnt) + orders buffer reuse
  }

  float Li = 1.0f / L;
  size_t rowbase = ((size_t)(b * Tv + qrow)) * Cv + h * HDv;
#pragma unroll
  for (int dt = 0; dt < 8; dt++) {
    unsigned int lo = (unsigned int)f2b(o[dt][0] * Li) | ((unsigned int)f2b(o[dt][1] * Li) << 16);
    unsigned int hi2 = (unsigned int)f2b(o[dt][2] * Li) | ((unsigned int)f2b(o[dt][3] * Li) << 16);
    *(uint2*)(&ys[rowbase + dt * 16 + quad * 4]) = make_uint2(lo, hi2);
  }
}

// ---------------- output projection: dbuf LDS + cross-barrier prefetch ----------------
__global__ __launch_bounds__(256) void gemm_proj(
    const unsigned short* __restrict__ ys,
    const unsigned short* __restrict__ wp_t,  // 2048 x 2048 (N-major)
    const float* __restrict__ bp,
    float* __restrict__ out) {
  __shared__ __align__(16) unsigned short Ash[2][128 * 32];
  __shared__ __align__(16) unsigned short Bsh[2][128 * 32];
  int tid = threadIdx.x;
  int wave = tid >> 6, lane = tid & 63;
  int c = lane & 15, quad = lane >> 4;
  int wr = (wave >> 1) * 64, wc = (wave & 1) * 64;
  int m0 = blockIdx.x * 128, n0 = blockIdx.y * 128;
  floatx4 zero4 = {0.f, 0.f, 0.f, 0.f};
  floatx4 acc[4][4];
#pragma unroll
  for (int i = 0; i < 4; i++)
#pragma unroll
    for (int j = 0; j < 4; j++) acc[i][j] = zero4;

  const unsigned short* Abase = ys + (size_t)m0 * 2048;
  const unsigned short* Bbase = wp_t + (size_t)n0 * 2048;
  int s0 = wave * 128 + lane, s1 = wave * 128 + 64 + lane;
  int r0 = s0 >> 2, kc0 = (s0 & 3) ^ (r0 & 3);
  int r1 = s1 >> 2, kc1 = (s1 & 3) ^ (r1 & 3);
  int swz3 = quad ^ (c & 3);
  int dA0 = (wave * 128) * 8, dA1 = (wave * 128 + 64) * 8;

  gld_lds16(Abase + (size_t)r0 * 2048 + kc0 * 8, &Ash[0][0] + dA0);
  gld_lds16(Abase + (size_t)r1 * 2048 + kc1 * 8, &Ash[0][0] + dA1);
  gld_lds16(Bbase + (size_t)r0 * 2048 + kc0 * 8, &Bsh[0][0] + dA0);
  gld_lds16(Bbase + (size_t)r1 * 2048 + kc1 * 8, &Bsh[0][0] + dA1);
  __syncthreads();

  for (int it = 0; it < 64; it++) {
    int cur = it & 1;
    if (it + 1 < 64) {
      int k1 = (it + 1) * 32;
      gld_lds16(Abase + (size_t)r0 * 2048 + k1 + kc0 * 8, &Ash[cur ^ 1][0] + dA0);
      gld_lds16(Abase + (size_t)r1 * 2048 + k1 + kc1 * 8, &Ash[cur ^ 1][0] + dA1);
      gld_lds16(Bbase + (size_t)r0 * 2048 + k1 + kc0 * 8, &Bsh[cur ^ 1][0] + dA0);
      gld_lds16(Bbase + (size_t)r1 * 2048 + k1 + kc1 * 8, &Bsh[cur ^ 1][0] + dA1);
    }
    bf16x8 af[4], bfv[4];
#pragma unroll
    for (int i = 0; i < 4; i++)
      af[i] = *(const bf16x8*)(&Ash[cur][(wr + i * 16 + c) * 32 + swz3 * 8]);
#pragma unroll
    for (int j = 0; j < 4; j++)
      bfv[j] = *(const bf16x8*)(&Bsh[cur][(wc + j * 16 + c) * 32 + swz3 * 8]);
#pragma unroll
    for (int i = 0; i < 4; i++)
#pragma unroll
      for (int j = 0; j < 4; j++)
        acc[i][j] = MFMA(af[i], bfv[j], acc[i][j]);
    __syncthreads();
  }

#pragma unroll
  for (int i = 0; i < 4; i++) {
#pragma unroll
    for (int j = 0; j < 4; j++) {
#pragma unroll
      for (int r = 0; r < 4; r++) {
        int m = m0 + wr + i * 16 + quad * 4 + r;
        int n = n0 + wc + j * 16 + c;
        out[(size_t)m * 2048 + n] = acc[i][j][r] + bp[n];
      }
    }
  }
}

extern "C" void kernel_launch(void* const* d_in, const int* in_sizes, int n_in,
                              void* d_out, int out_size, void* d_ws, size_t ws_size,
                              hipStream_t stream) {
  (void)in_sizes; (void)n_in; (void)out_size; (void)ws_size;
  const float* x   = (const float*)d_in[0];
  const float* Wkv = (const float*)d_in[1];
  const float* bkv = (const float*)d_in[2];
  const float* Wq  = (const float*)d_in[3];
  const float* bq  = (const float*)d_in[4];
  const float* Wp  = (const float*)d_in[5];
  const float* bp  = (const float*)d_in[6];
  float* out = (float*)d_out;

  char* ws = (char*)d_ws;
  unsigned short* xb    = (unsigned short*)(ws + 0);          // 16.78 MB
  unsigned short* wq_t  = (unsigned short*)(ws + 16777216);   //  8.39 MB
  unsigned short* wkv_t = (unsigned short*)(ws + 25165824);   //  4.19 MB
  unsigned short* wp_t  = (unsigned short*)(ws + 29360128);   //  8.39 MB
  unsigned short* qs    = (unsigned short*)(ws + 37748736);   // 16.78 MB
  unsigned short* ks    = (unsigned short*)(ws + 54525952);   //  4.19 MB
  unsigned short* vs    = (unsigned short*)(ws + 58720256);   //  4.19 MB
  unsigned short* ysbuf = (unsigned short*)(ws + 62914560);   // 16.78 MB  (end 79.7 MB)

  cvt_kernel<<<8192, 256, 0, stream>>>(x, xb, 2097152);
  tcvt_kernel<<<dim3(64, 64), dim3(32, 8), 0, stream>>>(Wq, wq_t, 2048, 2048);
  tcvt_kernel<<<dim3(64, 32), dim3(32, 8), 0, stream>>>(Wkv, wkv_t, 2048, 1024);
  tcvt_kernel<<<dim3(64, 64), dim3(32, 8), 0, stream>>>(Wp, wp_t, 2048, 2048);
  gemm_qkv<<<dim3(32, 24), 256, 0, stream>>>(xb, wq_t, wkv_t, bq, bkv, qs, ks, vs);
  attn_kernel<<<dim3(32, 16, 2), 256, 0, stream>>>(qs, ks, vs, ysbuf);
  gemm_proj<<<dim3(32, 16), 256, 0, stream>>>(ysbuf, wp_t, bp, out);
}